// Round 2
// baseline (832.064 us; speedup 1.0000x reference)
//
#include <hip/hip_runtime.h>

#define N_NODES 100000
#define N_EDGES 1600000

static constexpr float BN_EPS = 1e-5f;
static constexpr float SLOPE = 0.3f;

// ---------------------------------------------------------------------------
// Pass 1: per-node transforms.
//   A[n] = feat[n] @ (W1 - W2)^T + b      (W1 = W[:, :64], W2 = W[:, 64:])
//   B[n] = feat[n] @ W2^T
// so that per edge:  m_e = A[dst_e] + B[src_e]
// A is stored in d_out (same shape as the output; rewritten at the end).
// ---------------------------------------------------------------------------
__global__ __launch_bounds__(256) void node_transform_kernel(
    const float* __restrict__ feat, const float* __restrict__ W,
    const float* __restrict__ bias, float* __restrict__ A,
    float* __restrict__ Bm) {
  __shared__ float Wa[64][64];  // [k][c] layout: lane==c -> 2-way alias (free)
  __shared__ float Wb[64][64];
  int t = threadIdx.x;
  for (int i = t; i < 64 * 64; i += 256) {
    int c = i >> 6, k = i & 63;
    float w1 = W[c * 128 + k];
    float w2 = W[c * 128 + 64 + k];
    Wa[k][c] = w1 - w2;
    Wb[k][c] = w2;
  }
  __syncthreads();

  int lane = t & 63;
  int wv = t >> 6;
  int gwave = blockIdx.x * 4 + wv;
  int nwaves = gridDim.x * 4;
  float bc = bias[lane];

  for (int n = gwave; n < N_NODES; n += nwaves) {
    float v = feat[n * 64 + lane];  // coalesced row load
    float a = bc;
    float bb = 0.f;
#pragma unroll
    for (int k = 0; k < 64; ++k) {
      float fv = __shfl(v, k, 64);  // broadcast feat[n][k]
      a += fv * Wa[k][lane];
      bb += fv * Wb[k][lane];
    }
    A[n * 64 + lane] = a;
    Bm[n * 64 + lane] = bb;
  }
}

// ---------------------------------------------------------------------------
// CSR build: degree histogram -> 1-block scan -> cursor scatter (dst-sorted
// src indices). Int atomics over L2-resident 400 KB arrays: cheap.
// ---------------------------------------------------------------------------
__global__ __launch_bounds__(256) void degree_kernel(const int* __restrict__ ei,
                                                     int* __restrict__ deg) {
  int e = blockIdx.x * 256 + threadIdx.x;
  if (e < N_EDGES) atomicAdd(&deg[ei[N_EDGES + e]], 1);  // dst
}

__global__ __launch_bounds__(1024) void scan_kernel(const int* __restrict__ deg,
                                                    int* __restrict__ row_ptr,
                                                    int* __restrict__ cursor) {
  __shared__ int part[1024];
  int t = threadIdx.x;
  const int CH = (N_NODES + 1023) / 1024;  // 98
  int lo = t * CH;
  int hi = min(lo + CH, N_NODES);
  int s = 0;
  for (int i = lo; i < hi; ++i) s += deg[i];
  part[t] = s;
  __syncthreads();
  for (int off = 1; off < 1024; off <<= 1) {  // Hillis-Steele inclusive scan
    int v = (t >= off) ? part[t - off] : 0;
    __syncthreads();
    part[t] += v;
    __syncthreads();
  }
  int run = (t == 0) ? 0 : part[t - 1];
  for (int i = lo; i < hi; ++i) {
    row_ptr[i] = run;
    cursor[i] = run;
    run += deg[i];
  }
  if (t == 1023) row_ptr[N_NODES] = part[1023];
}

__global__ __launch_bounds__(256) void scatter_kernel(const int* __restrict__ ei,
                                                      int* __restrict__ cursor,
                                                      int* __restrict__ esrc) {
  int e = blockIdx.x * 256 + threadIdx.x;
  if (e < N_EDGES) {
    int d = ei[N_EDGES + e];
    int p = atomicAdd(&cursor[d], 1);
    esrc[p] = ei[e];  // src
  }
}

// ---------------------------------------------------------------------------
// Pass 2: BN statistics, pull-based. Wave per node; lane = channel.
// A row is register-resident; only B[src] rows are gathered.
// ---------------------------------------------------------------------------
__global__ __launch_bounds__(256) void stats_kernel(
    const int* __restrict__ row_ptr, const int* __restrict__ esrc,
    const float* __restrict__ A, const float* __restrict__ Bm,
    float* __restrict__ sums) {
  int lane = threadIdx.x & 63;
  int wv = threadIdx.x >> 6;
  int gwave = blockIdx.x * 4 + wv;
  int nwaves = gridDim.x * 4;

  float s = 0.f, sq = 0.f;
  for (int n = gwave; n < N_NODES; n += nwaves) {
    float a = A[n * 64 + lane];
    int lo = row_ptr[n], hi = row_ptr[n + 1];
    for (int j = lo; j < hi; ++j) {
      int sidx = esrc[j];  // wave-uniform broadcast load
      float m = a + Bm[sidx * 64 + lane];
      s += m;
      sq += m * m;
    }
  }
  __shared__ float ls[4][64];
  __shared__ float lq[4][64];
  ls[wv][lane] = s;
  lq[wv][lane] = sq;
  __syncthreads();
  if (wv == 0) {
    atomicAdd(&sums[lane], ls[0][lane] + ls[1][lane] + ls[2][lane] + ls[3][lane]);
    atomicAdd(&sums[64 + lane],
              lq[0][lane] + lq[1][lane] + lq[2][lane] + lq[3][lane]);
  }
}

__global__ __launch_bounds__(64) void bn_params_kernel(
    const float* __restrict__ sums, const float* __restrict__ gamma,
    const float* __restrict__ beta, float* __restrict__ ss) {
  int c = threadIdx.x;
  const float invE = 1.0f / (float)N_EDGES;
  float mu = sums[c] * invE;
  float var = sums[64 + c] * invE - mu * mu;
  float rs = rsqrtf(var + BN_EPS);
  float sc = gamma[c] * rs;
  ss[c] = sc;
  ss[64 + c] = beta[c] - mu * sc;
}

// ---------------------------------------------------------------------------
// Pass 3: aggregation, pull-based. Wave per node; no atomics; out written
// exactly once per row (zero rows for isolated nodes).
// ---------------------------------------------------------------------------
__global__ __launch_bounds__(256) void aggregate_kernel(
    const int* __restrict__ row_ptr, const int* __restrict__ esrc,
    const float* __restrict__ A, const float* __restrict__ Bm,
    const float* __restrict__ ss, float* __restrict__ out) {
  int lane = threadIdx.x & 63;
  int wv = threadIdx.x >> 6;
  int gwave = blockIdx.x * 4 + wv;
  int nwaves = gridDim.x * 4;

  float sc = ss[lane];
  float sh = ss[64 + lane];

  for (int n = gwave; n < N_NODES; n += nwaves) {
    float a = A[n * 64 + lane];  // A aliases out: read before write
    int lo = row_ptr[n], hi = row_ptr[n + 1];
    float acc = 0.f;
    for (int j = lo; j < hi; ++j) {
      int sidx = esrc[j];
      float m = a + Bm[sidx * 64 + lane];
      float y = m * sc + sh;
      acc += (y >= 0.f) ? y : SLOPE * y;
    }
    int cnt = hi - lo;
    out[n * 64 + lane] = acc * (1.0f / (float)max(cnt, 1));
  }
}

extern "C" void kernel_launch(void* const* d_in, const int* in_sizes, int n_in,
                              void* d_out, int out_size, void* d_ws,
                              size_t ws_size, hipStream_t stream) {
  const float* feat = (const float*)d_in[0];
  const int* ei = (const int*)d_in[1];
  const float* W = (const float*)d_in[2];
  const float* b = (const float*)d_in[3];
  const float* gamma = (const float*)d_in[4];
  const float* beta = (const float*)d_in[5];
  float* out = (float*)d_out;

  // A lives in d_out (exact same shape; final pass overwrites it in place).
  float* A = out;

  // Workspace layout
  float* Bm = (float*)d_ws;                    // 6,400,000 f
  float* sums = Bm + (size_t)N_NODES * 64;     // 128 f
  float* ss = sums + 128;                      // 128 f
  int* deg = (int*)(ss + 128);                 // N ints
  int* row_ptr = deg + N_NODES;                // N+1 ints
  int* cursor = row_ptr + N_NODES + 1;         // N ints
  int* esrc = cursor + N_NODES;                // E ints
  // total ~33.3 MB (< the ~51.6 MB round-1 footprint that fit)

  hipMemsetAsync(deg, 0, (size_t)N_NODES * sizeof(int), stream);
  hipMemsetAsync(sums, 0, 128 * sizeof(float), stream);

  node_transform_kernel<<<1024, 256, 0, stream>>>(feat, W, b, A, Bm);
  degree_kernel<<<(N_EDGES + 255) / 256, 256, 0, stream>>>(ei, deg);
  scan_kernel<<<1, 1024, 0, stream>>>(deg, row_ptr, cursor);
  scatter_kernel<<<(N_EDGES + 255) / 256, 256, 0, stream>>>(ei, cursor, esrc);
  stats_kernel<<<2048, 256, 0, stream>>>(row_ptr, esrc, A, Bm, sums);
  bn_params_kernel<<<1, 64, 0, stream>>>(sums, gamma, beta, ss);
  aggregate_kernel<<<2048, 256, 0, stream>>>(row_ptr, esrc, A, Bm, ss, out);
}

// Round 3
// 463.957 us; speedup vs baseline: 1.7934x; 1.7934x over previous
//
#include <hip/hip_runtime.h>

#define N_NODES 100000
#define N_EDGES 1600000

static constexpr float BN_EPS = 1e-5f;
static constexpr float SLOPE = 0.3f;

// ---------------------------------------------------------------------------
// Pass 1: per-node transforms.
//   A[n] = feat[n] @ (W1 - W2)^T + b      (W1 = W[:, :64], W2 = W[:, 64:])
//   B[n] = feat[n] @ W2^T
// Per edge: m_e = A[dst_e] + B[src_e].  A lives in d_out (rewritten later).
// ---------------------------------------------------------------------------
__global__ __launch_bounds__(256) void node_transform_kernel(
    const float* __restrict__ feat, const float* __restrict__ W,
    const float* __restrict__ bias, float* __restrict__ A,
    float* __restrict__ Bm) {
  __shared__ float Wa[64][64];  // [k][c]: lane==c -> 2-way alias (free)
  __shared__ float Wb[64][64];
  int t = threadIdx.x;
  for (int i = t; i < 64 * 64; i += 256) {
    int c = i >> 6, k = i & 63;
    float w1 = W[c * 128 + k];
    float w2 = W[c * 128 + 64 + k];
    Wa[k][c] = w1 - w2;
    Wb[k][c] = w2;
  }
  __syncthreads();

  int lane = t & 63;
  int wv = t >> 6;
  int gwave = blockIdx.x * 4 + wv;
  int nwaves = gridDim.x * 4;
  float bc = bias[lane];

  for (int n = gwave; n < N_NODES; n += nwaves) {
    float v = feat[n * 64 + lane];
    float a = bc;
    float bb = 0.f;
#pragma unroll
    for (int k = 0; k < 64; ++k) {
      float fv = __shfl(v, k, 64);
      a += fv * Wa[k][lane];
      bb += fv * Wb[k][lane];
    }
    A[n * 64 + lane] = a;
    Bm[n * 64 + lane] = bb;
  }
}

// ---------------------------------------------------------------------------
// CSR build: degree histogram -> 3-dispatch parallel scan -> cursor scatter.
// ---------------------------------------------------------------------------
__global__ __launch_bounds__(256) void degree_kernel(const int* __restrict__ ei,
                                                     int* __restrict__ deg) {
  int e = blockIdx.x * 256 + threadIdx.x;
  if (e < N_EDGES) atomicAdd(&deg[ei[N_EDGES + e]], 1);  // dst
}

// Level 1: per-block (1024-wide) exclusive scan, emit block sums.
__global__ __launch_bounds__(1024) void scan1_kernel(const int* __restrict__ deg,
                                                     int* __restrict__ pre,
                                                     int* __restrict__ bsum) {
  __shared__ int sh[1024];
  int t = threadIdx.x;
  int i = blockIdx.x * 1024 + t;
  int v = (i < N_NODES) ? deg[i] : 0;
  sh[t] = v;
  __syncthreads();
  for (int off = 1; off < 1024; off <<= 1) {
    int u = (t >= off) ? sh[t - off] : 0;
    __syncthreads();
    sh[t] += u;
    __syncthreads();
  }
  if (i < N_NODES) pre[i] = sh[t] - v;  // exclusive within block
  if (t == 1023) bsum[blockIdx.x] = sh[1023];
}

// Level 2: single block scans the (<=128) block sums -> exclusive.
__global__ __launch_bounds__(128) void scan2_kernel(int* __restrict__ bsum,
                                                    int nb) {
  __shared__ int sh[128];
  int t = threadIdx.x;
  int v = (t < nb) ? bsum[t] : 0;
  sh[t] = v;
  __syncthreads();
  for (int off = 1; off < 128; off <<= 1) {
    int u = (t >= off) ? sh[t - off] : 0;
    __syncthreads();
    sh[t] += u;
    __syncthreads();
  }
  if (t < nb) bsum[t] = sh[t] - v;  // exclusive
}

// Level 3: add block offsets, init cursor, set row_ptr[N].
__global__ __launch_bounds__(256) void scan3_kernel(const int* __restrict__ pre,
                                                    const int* __restrict__ bsum,
                                                    int* __restrict__ row_ptr,
                                                    int* __restrict__ cursor) {
  int i = blockIdx.x * 256 + threadIdx.x;
  if (i < N_NODES) {
    int r = pre[i] + bsum[i >> 10];
    row_ptr[i] = r;
    cursor[i] = r;
  }
  if (i == 0) row_ptr[N_NODES] = N_EDGES;
}

__global__ __launch_bounds__(256) void scatter_kernel(const int* __restrict__ ei,
                                                      int* __restrict__ cursor,
                                                      int* __restrict__ esrc) {
  int e = blockIdx.x * 256 + threadIdx.x;
  if (e < N_EDGES) {
    int d = ei[N_EDGES + e];
    int p = atomicAdd(&cursor[d], 1);
    esrc[p] = ei[e];  // src
  }
}

// ---------------------------------------------------------------------------
// Pass 2: BN statistics, pull-based. Wave per node; lane = channel.
// Coalesced esrc batch load + shfl broadcast + 4-deep pipelined B gathers.
// ---------------------------------------------------------------------------
__global__ __launch_bounds__(256) void stats_kernel(
    const int* __restrict__ row_ptr, const int* __restrict__ esrc,
    const float* __restrict__ A, const float* __restrict__ Bm,
    float* __restrict__ sums) {
  int lane = threadIdx.x & 63;
  int wv = threadIdx.x >> 6;
  int gwave = blockIdx.x * 4 + wv;
  int nwaves = gridDim.x * 4;

  float s = 0.f, sq = 0.f;
  for (int n = gwave; n < N_NODES; n += nwaves) {
    float a = A[n * 64 + lane];
    int lo = row_ptr[n], hi = row_ptr[n + 1];
    for (int base = lo; base < hi; base += 64) {
      int nb = min(64, hi - base);
      int sidx = (lane < nb) ? esrc[base + lane] : 0;  // coalesced
      int k = 0;
      for (; k + 4 <= nb; k += 4) {
        int s0 = __shfl(sidx, k);
        int s1 = __shfl(sidx, k + 1);
        int s2 = __shfl(sidx, k + 2);
        int s3 = __shfl(sidx, k + 3);
        float g0 = Bm[s0 * 64 + lane];  // 4 independent gathers in flight
        float g1 = Bm[s1 * 64 + lane];
        float g2 = Bm[s2 * 64 + lane];
        float g3 = Bm[s3 * 64 + lane];
        float m0 = a + g0, m1 = a + g1, m2 = a + g2, m3 = a + g3;
        s += (m0 + m1) + (m2 + m3);
        sq += m0 * m0;
        sq += m1 * m1;
        sq += m2 * m2;
        sq += m3 * m3;
      }
      for (; k < nb; ++k) {
        int s0 = __shfl(sidx, k);
        float m = a + Bm[s0 * 64 + lane];
        s += m;
        sq += m * m;
      }
    }
  }
  __shared__ float ls[4][64];
  __shared__ float lq[4][64];
  ls[wv][lane] = s;
  lq[wv][lane] = sq;
  __syncthreads();
  if (wv == 0) {
    atomicAdd(&sums[lane], ls[0][lane] + ls[1][lane] + ls[2][lane] + ls[3][lane]);
    atomicAdd(&sums[64 + lane],
              lq[0][lane] + lq[1][lane] + lq[2][lane] + lq[3][lane]);
  }
}

__global__ __launch_bounds__(64) void bn_params_kernel(
    const float* __restrict__ sums, const float* __restrict__ gamma,
    const float* __restrict__ beta, float* __restrict__ ss) {
  int c = threadIdx.x;
  const float invE = 1.0f / (float)N_EDGES;
  float mu = sums[c] * invE;
  float var = sums[64 + c] * invE - mu * mu;
  float rs = rsqrtf(var + BN_EPS);
  float sc = gamma[c] * rs;
  ss[c] = sc;
  ss[64 + c] = beta[c] - mu * sc;
}

// ---------------------------------------------------------------------------
// Pass 3: aggregation, pull-based, same pipelined-gather structure.
// ---------------------------------------------------------------------------
__global__ __launch_bounds__(256) void aggregate_kernel(
    const int* __restrict__ row_ptr, const int* __restrict__ esrc,
    const float* __restrict__ A, const float* __restrict__ Bm,
    const float* __restrict__ ss, float* __restrict__ out) {
  int lane = threadIdx.x & 63;
  int wv = threadIdx.x >> 6;
  int gwave = blockIdx.x * 4 + wv;
  int nwaves = gridDim.x * 4;

  float sc = ss[lane];
  float sh = ss[64 + lane];

  for (int n = gwave; n < N_NODES; n += nwaves) {
    float a = A[n * 64 + lane];  // A aliases out: read before write
    int lo = row_ptr[n], hi = row_ptr[n + 1];
    float acc = 0.f;
    for (int base = lo; base < hi; base += 64) {
      int nb = min(64, hi - base);
      int sidx = (lane < nb) ? esrc[base + lane] : 0;
      int k = 0;
      for (; k + 4 <= nb; k += 4) {
        int s0 = __shfl(sidx, k);
        int s1 = __shfl(sidx, k + 1);
        int s2 = __shfl(sidx, k + 2);
        int s3 = __shfl(sidx, k + 3);
        float g0 = Bm[s0 * 64 + lane];
        float g1 = Bm[s1 * 64 + lane];
        float g2 = Bm[s2 * 64 + lane];
        float g3 = Bm[s3 * 64 + lane];
        float y0 = fmaf(a + g0, sc, sh);
        float y1 = fmaf(a + g1, sc, sh);
        float y2 = fmaf(a + g2, sc, sh);
        float y3 = fmaf(a + g3, sc, sh);
        y0 = (y0 >= 0.f) ? y0 : SLOPE * y0;
        y1 = (y1 >= 0.f) ? y1 : SLOPE * y1;
        y2 = (y2 >= 0.f) ? y2 : SLOPE * y2;
        y3 = (y3 >= 0.f) ? y3 : SLOPE * y3;
        acc += (y0 + y1) + (y2 + y3);
      }
      for (; k < nb; ++k) {
        int s0 = __shfl(sidx, k);
        float y = fmaf(a + Bm[s0 * 64 + lane], sc, sh);
        acc += (y >= 0.f) ? y : SLOPE * y;
      }
    }
    int cnt = hi - lo;
    out[n * 64 + lane] = acc * (1.0f / (float)max(cnt, 1));
  }
}

extern "C" void kernel_launch(void* const* d_in, const int* in_sizes, int n_in,
                              void* d_out, int out_size, void* d_ws,
                              size_t ws_size, hipStream_t stream) {
  const float* feat = (const float*)d_in[0];
  const int* ei = (const int*)d_in[1];
  const float* W = (const float*)d_in[2];
  const float* b = (const float*)d_in[3];
  const float* gamma = (const float*)d_in[4];
  const float* beta = (const float*)d_in[5];
  float* out = (float*)d_out;

  float* A = out;  // A lives in d_out; final pass overwrites in place

  // Workspace layout
  float* Bm = (float*)d_ws;                 // 6,400,000 f
  float* sums = Bm + (size_t)N_NODES * 64;  // 128 f
  float* ss = sums + 128;                   // 128 f
  int* deg = (int*)(ss + 128);              // N
  int* row_ptr = deg + N_NODES;             // N+1
  int* cursor = row_ptr + N_NODES + 1;      // N
  int* pre = cursor + N_NODES;              // N
  int* bsum = pre + N_NODES;                // 128
  int* esrc = bsum + 128;                   // E
  // total ~34 MB

  const int NB_SCAN = (N_NODES + 1023) / 1024;  // 98

  hipMemsetAsync(deg, 0, (size_t)N_NODES * sizeof(int), stream);
  hipMemsetAsync(sums, 0, 128 * sizeof(float), stream);

  node_transform_kernel<<<1024, 256, 0, stream>>>(feat, W, b, A, Bm);
  degree_kernel<<<(N_EDGES + 255) / 256, 256, 0, stream>>>(ei, deg);
  scan1_kernel<<<NB_SCAN, 1024, 0, stream>>>(deg, pre, bsum);
  scan2_kernel<<<1, 128, 0, stream>>>(bsum, NB_SCAN);
  scan3_kernel<<<(N_NODES + 255) / 256, 256, 0, stream>>>(pre, bsum, row_ptr,
                                                          cursor);
  scatter_kernel<<<(N_EDGES + 255) / 256, 256, 0, stream>>>(ei, cursor, esrc);
  stats_kernel<<<2048, 256, 0, stream>>>(row_ptr, esrc, A, Bm, sums);
  bn_params_kernel<<<1, 64, 0, stream>>>(sums, gamma, beta, ss);
  aggregate_kernel<<<2048, 256, 0, stream>>>(row_ptr, esrc, A, Bm, ss, out);
}

// Round 4
// 369.364 us; speedup vs baseline: 2.2527x; 1.2561x over previous
//
#include <hip/hip_runtime.h>

#define N_NODES 100000
#define N_EDGES 1600000
#define NBUCK 196   // ceil(N_NODES / 512)
#define EPB 4096    // edges per block in bucket_scatter
#define CAPB 9500   // LDS staging capacity in bucket_sort (mean 8192, sigma ~90)

static constexpr float BN_EPS = 1e-5f;
static constexpr float SLOPE = 0.3f;

// ---------------------------------------------------------------------------
// Pass 1: per-node transforms.
//   A[n] = feat[n] @ (W1 - W2)^T + b      (W1 = W[:, :64], W2 = W[:, 64:])
//   B[n] = feat[n] @ W2^T
// Per edge: m_e = A[dst_e] + B[src_e].  A lives in d_out (rewritten later).
// ---------------------------------------------------------------------------
__global__ __launch_bounds__(256) void node_transform_kernel(
    const float* __restrict__ feat, const float* __restrict__ W,
    const float* __restrict__ bias, float* __restrict__ A,
    float* __restrict__ Bm) {
  __shared__ float Wa[64][64];  // [k][c]: lane==c -> 2-way alias (free)
  __shared__ float Wb[64][64];
  int t = threadIdx.x;
  for (int i = t; i < 64 * 64; i += 256) {
    int c = i >> 6, k = i & 63;
    float w1 = W[c * 128 + k];
    float w2 = W[c * 128 + 64 + k];
    Wa[k][c] = w1 - w2;
    Wb[k][c] = w2;
  }
  __syncthreads();

  int lane = t & 63;
  int wv = t >> 6;
  int gwave = blockIdx.x * 4 + wv;
  int nwaves = gridDim.x * 4;
  float bc = bias[lane];

  for (int n = gwave; n < N_NODES; n += nwaves) {
    float v = feat[n * 64 + lane];
    float a = bc;
    float bb = 0.f;
#pragma unroll
    for (int k = 0; k < 64; ++k) {
      float fv = __shfl(v, k, 64);
      a += fv * Wa[k][lane];
      bb += fv * Wb[k][lane];
    }
    A[n * 64 + lane] = a;
    Bm[n * 64 + lane] = bb;
  }
}

// ---------------------------------------------------------------------------
// CSR build: degree histogram -> 3-dispatch parallel scan.
// ---------------------------------------------------------------------------
__global__ __launch_bounds__(256) void degree_kernel(const int* __restrict__ ei,
                                                     int* __restrict__ deg) {
  int e = blockIdx.x * 256 + threadIdx.x;
  if (e < N_EDGES) atomicAdd(&deg[ei[N_EDGES + e]], 1);  // dst
}

__global__ __launch_bounds__(1024) void scan1_kernel(const int* __restrict__ deg,
                                                     int* __restrict__ pre,
                                                     int* __restrict__ bsum) {
  __shared__ int sh[1024];
  int t = threadIdx.x;
  int i = blockIdx.x * 1024 + t;
  int v = (i < N_NODES) ? deg[i] : 0;
  sh[t] = v;
  __syncthreads();
  for (int off = 1; off < 1024; off <<= 1) {
    int u = (t >= off) ? sh[t - off] : 0;
    __syncthreads();
    sh[t] += u;
    __syncthreads();
  }
  if (i < N_NODES) pre[i] = sh[t] - v;  // exclusive within block
  if (t == 1023) bsum[blockIdx.x] = sh[1023];
}

__global__ __launch_bounds__(128) void scan2_kernel(int* __restrict__ bsum,
                                                    int nb) {
  __shared__ int sh[128];
  int t = threadIdx.x;
  int v = (t < nb) ? bsum[t] : 0;
  sh[t] = v;
  __syncthreads();
  for (int off = 1; off < 128; off <<= 1) {
    int u = (t >= off) ? sh[t - off] : 0;
    __syncthreads();
    sh[t] += u;
    __syncthreads();
  }
  if (t < nb) bsum[t] = sh[t] - v;  // exclusive
}

// Level 3: materialize row_ptr; init per-bucket global cursors to bucket base.
__global__ __launch_bounds__(256) void scan3_kernel(const int* __restrict__ pre,
                                                    const int* __restrict__ bsum,
                                                    int* __restrict__ row_ptr,
                                                    int* __restrict__ gcur) {
  int i = blockIdx.x * 256 + threadIdx.x;
  if (i < N_NODES) {
    int r = pre[i] + bsum[i >> 10];
    row_ptr[i] = r;
    if ((i & 511) == 0) gcur[i >> 9] = r;  // bucket base cursor
  }
  if (i == 0) row_ptr[N_NODES] = N_EDGES;
}

// ---------------------------------------------------------------------------
// B1: coarse bucket scatter. Block-aggregated reservation (LDS histogram +
// one global atomic per (block,bucket)) -> packed (ldst<<17|src) written in
// ~84B contiguous runs inside each bucket's exact final region. No random
// 4B write-allocate traffic.
// ---------------------------------------------------------------------------
__global__ __launch_bounds__(256) void bucket_scatter_kernel(
    const int* __restrict__ ei, int* __restrict__ gcur,
    unsigned* __restrict__ pbuf) {
  __shared__ int base[NBUCK];
  __shared__ int hist[NBUCK];
  int t = threadIdx.x;
  int e0 = blockIdx.x * EPB;
  int nE = min(EPB, N_EDGES - e0);

  for (int i = t; i < NBUCK; i += 256) hist[i] = 0;
  __syncthreads();
  for (int i = t; i < nE; i += 256) {
    int d = ei[N_EDGES + e0 + i];
    atomicAdd(&hist[d >> 9], 1);
  }
  __syncthreads();
  for (int i = t; i < NBUCK; i += 256) {
    int h = hist[i];
    base[i] = h ? atomicAdd(&gcur[i], h) : 0;
    hist[i] = 0;  // reuse as local cursor
  }
  __syncthreads();
  for (int i = t; i < nE; i += 256) {
    int d = ei[N_EDGES + e0 + i];
    int s = ei[e0 + i];
    int b = d >> 9;
    int off = atomicAdd(&hist[b], 1);
    pbuf[base[b] + off] = ((unsigned)(d & 511) << 17) | (unsigned)s;
  }
}

// ---------------------------------------------------------------------------
// B2: per-bucket fine sort. Per-node offsets come free from row_ptr; scatter
// into LDS staging, then one coalesced copy to esrc. Direct-global fallback
// keeps correctness for pathological degree distributions.
// ---------------------------------------------------------------------------
__global__ __launch_bounds__(1024) void bucket_sort_kernel(
    const int* __restrict__ row_ptr, const unsigned* __restrict__ pbuf,
    int* __restrict__ esrc) {
  __shared__ int pref[512];
  __shared__ int cur[512];
  __shared__ int buf[CAPB];
  int t = threadIdx.x;
  int node0 = blockIdx.x << 9;
  int nn = min(512, N_NODES - node0);
  int fbase = row_ptr[node0];
  int fend = row_ptr[min(node0 + 512, N_NODES)];
  int m = fend - fbase;
  if (t < nn) {
    pref[t] = row_ptr[node0 + t] - fbase;
    cur[t] = 0;
  }
  __syncthreads();
  for (int i = t; i < m; i += 1024) {
    unsigned v = pbuf[fbase + i];
    int ldst = v >> 17;
    int src = (int)(v & 0x1FFFFu);
    int pos = pref[ldst] + atomicAdd(&cur[ldst], 1);
    if (pos < CAPB) buf[pos] = src;
    else esrc[fbase + pos] = src;  // overflow fallback (statistically never)
  }
  __syncthreads();
  int lim = min(m, CAPB);
  for (int i = t; i < lim; i += 1024) esrc[fbase + i] = buf[i];
}

// ---------------------------------------------------------------------------
// Pass 2: BN statistics, pull-based. Wave per node; lane = channel.
// Coalesced esrc batch load + shfl broadcast + 4-deep pipelined B gathers.
// ---------------------------------------------------------------------------
__global__ __launch_bounds__(256) void stats_kernel(
    const int* __restrict__ row_ptr, const int* __restrict__ esrc,
    const float* __restrict__ A, const float* __restrict__ Bm,
    float* __restrict__ sums) {
  int lane = threadIdx.x & 63;
  int wv = threadIdx.x >> 6;
  int gwave = blockIdx.x * 4 + wv;
  int nwaves = gridDim.x * 4;

  float s = 0.f, sq = 0.f;
  for (int n = gwave; n < N_NODES; n += nwaves) {
    float a = A[n * 64 + lane];
    int lo = row_ptr[n], hi = row_ptr[n + 1];
    for (int base = lo; base < hi; base += 64) {
      int nb = min(64, hi - base);
      int sidx = (lane < nb) ? esrc[base + lane] : 0;  // coalesced
      int k = 0;
      for (; k + 4 <= nb; k += 4) {
        int s0 = __shfl(sidx, k);
        int s1 = __shfl(sidx, k + 1);
        int s2 = __shfl(sidx, k + 2);
        int s3 = __shfl(sidx, k + 3);
        float g0 = Bm[s0 * 64 + lane];  // 4 independent gathers in flight
        float g1 = Bm[s1 * 64 + lane];
        float g2 = Bm[s2 * 64 + lane];
        float g3 = Bm[s3 * 64 + lane];
        float m0 = a + g0, m1 = a + g1, m2 = a + g2, m3 = a + g3;
        s += (m0 + m1) + (m2 + m3);
        sq += m0 * m0;
        sq += m1 * m1;
        sq += m2 * m2;
        sq += m3 * m3;
      }
      for (; k < nb; ++k) {
        int s0 = __shfl(sidx, k);
        float m = a + Bm[s0 * 64 + lane];
        s += m;
        sq += m * m;
      }
    }
  }
  __shared__ float ls[4][64];
  __shared__ float lq[4][64];
  ls[wv][lane] = s;
  lq[wv][lane] = sq;
  __syncthreads();
  if (wv == 0) {
    atomicAdd(&sums[lane], ls[0][lane] + ls[1][lane] + ls[2][lane] + ls[3][lane]);
    atomicAdd(&sums[64 + lane],
              lq[0][lane] + lq[1][lane] + lq[2][lane] + lq[3][lane]);
  }
}

__global__ __launch_bounds__(64) void bn_params_kernel(
    const float* __restrict__ sums, const float* __restrict__ gamma,
    const float* __restrict__ beta, float* __restrict__ ss) {
  int c = threadIdx.x;
  const float invE = 1.0f / (float)N_EDGES;
  float mu = sums[c] * invE;
  float var = sums[64 + c] * invE - mu * mu;
  float rs = rsqrtf(var + BN_EPS);
  float sc = gamma[c] * rs;
  ss[c] = sc;
  ss[64 + c] = beta[c] - mu * sc;
}

// ---------------------------------------------------------------------------
// Pass 3: aggregation, pull-based, same pipelined-gather structure.
// ---------------------------------------------------------------------------
__global__ __launch_bounds__(256) void aggregate_kernel(
    const int* __restrict__ row_ptr, const int* __restrict__ esrc,
    const float* __restrict__ A, const float* __restrict__ Bm,
    const float* __restrict__ ss, float* __restrict__ out) {
  int lane = threadIdx.x & 63;
  int wv = threadIdx.x >> 6;
  int gwave = blockIdx.x * 4 + wv;
  int nwaves = gridDim.x * 4;

  float sc = ss[lane];
  float sh = ss[64 + lane];

  for (int n = gwave; n < N_NODES; n += nwaves) {
    float a = A[n * 64 + lane];  // A aliases out: read before write
    int lo = row_ptr[n], hi = row_ptr[n + 1];
    float acc = 0.f;
    for (int base = lo; base < hi; base += 64) {
      int nb = min(64, hi - base);
      int sidx = (lane < nb) ? esrc[base + lane] : 0;
      int k = 0;
      for (; k + 4 <= nb; k += 4) {
        int s0 = __shfl(sidx, k);
        int s1 = __shfl(sidx, k + 1);
        int s2 = __shfl(sidx, k + 2);
        int s3 = __shfl(sidx, k + 3);
        float g0 = Bm[s0 * 64 + lane];
        float g1 = Bm[s1 * 64 + lane];
        float g2 = Bm[s2 * 64 + lane];
        float g3 = Bm[s3 * 64 + lane];
        float y0 = fmaf(a + g0, sc, sh);
        float y1 = fmaf(a + g1, sc, sh);
        float y2 = fmaf(a + g2, sc, sh);
        float y3 = fmaf(a + g3, sc, sh);
        y0 = (y0 >= 0.f) ? y0 : SLOPE * y0;
        y1 = (y1 >= 0.f) ? y1 : SLOPE * y1;
        y2 = (y2 >= 0.f) ? y2 : SLOPE * y2;
        y3 = (y3 >= 0.f) ? y3 : SLOPE * y3;
        acc += (y0 + y1) + (y2 + y3);
      }
      for (; k < nb; ++k) {
        int s0 = __shfl(sidx, k);
        float y = fmaf(a + Bm[s0 * 64 + lane], sc, sh);
        acc += (y >= 0.f) ? y : SLOPE * y;
      }
    }
    int cnt = hi - lo;
    out[n * 64 + lane] = acc * (1.0f / (float)max(cnt, 1));
  }
}

extern "C" void kernel_launch(void* const* d_in, const int* in_sizes, int n_in,
                              void* d_out, int out_size, void* d_ws,
                              size_t ws_size, hipStream_t stream) {
  const float* feat = (const float*)d_in[0];
  const int* ei = (const int*)d_in[1];
  const float* W = (const float*)d_in[2];
  const float* b = (const float*)d_in[3];
  const float* gamma = (const float*)d_in[4];
  const float* beta = (const float*)d_in[5];
  float* out = (float*)d_out;

  float* A = out;  // A lives in d_out; final pass overwrites in place

  // Workspace layout (~40 MB)
  float* Bm = (float*)d_ws;                 // 6,400,000 f
  float* sums = Bm + (size_t)N_NODES * 64;  // 128 f
  float* ss = sums + 128;                   // 128 f
  int* deg = (int*)(ss + 128);              // N
  int* row_ptr = deg + N_NODES;             // N+1
  int* pre = row_ptr + N_NODES + 1;         // N
  int* bsum = pre + N_NODES;                // 128
  int* gcur = bsum + 128;                   // NBUCK
  unsigned* pbuf = (unsigned*)(gcur + NBUCK);  // E packed
  int* esrc = (int*)(pbuf + N_EDGES);       // E

  const int NB_SCAN = (N_NODES + 1023) / 1024;  // 98

  hipMemsetAsync(deg, 0, (size_t)N_NODES * sizeof(int), stream);
  hipMemsetAsync(sums, 0, 128 * sizeof(float), stream);

  node_transform_kernel<<<1024, 256, 0, stream>>>(feat, W, b, A, Bm);
  degree_kernel<<<(N_EDGES + 255) / 256, 256, 0, stream>>>(ei, deg);
  scan1_kernel<<<NB_SCAN, 1024, 0, stream>>>(deg, pre, bsum);
  scan2_kernel<<<1, 128, 0, stream>>>(bsum, NB_SCAN);
  scan3_kernel<<<(N_NODES + 255) / 256, 256, 0, stream>>>(pre, bsum, row_ptr,
                                                          gcur);
  bucket_scatter_kernel<<<(N_EDGES + EPB - 1) / EPB, 256, 0, stream>>>(ei, gcur,
                                                                       pbuf);
  bucket_sort_kernel<<<NBUCK, 1024, 0, stream>>>(row_ptr, pbuf, esrc);
  stats_kernel<<<2048, 256, 0, stream>>>(row_ptr, esrc, A, Bm, sums);
  bn_params_kernel<<<1, 64, 0, stream>>>(sums, gamma, beta, ss);
  aggregate_kernel<<<2048, 256, 0, stream>>>(row_ptr, esrc, A, Bm, ss, out);
}